// Round 2
// baseline (215.104 us; speedup 1.0000x reference)
//
#include <hip/hip_runtime.h>
#include <hip/hip_bf16.h>

// Problem constants
#define B_DIM 1024
#define L_DIM 32
#define K_DIM 8
#define G_DIM 8
#define C_DIM 128
#define S_DIM 32
#define DIN   104   // 2L + K + S

typedef __bf16  bf16x8 __attribute__((ext_vector_type(8)));
typedef float   f32x4  __attribute__((ext_vector_type(4)));

union frag_u { uint4 u; bf16x8 v; };

static __device__ __forceinline__ unsigned short f2b(float f) {
    union { float f; unsigned int i; } v; v.f = f;
    unsigned int x = v.i;
    return (unsigned short)((x + 0x7FFFu + ((x >> 16) & 1u)) >> 16);  // RNE
}
static __device__ __forceinline__ unsigned int pk2(float a, float b) {
    return (unsigned int)f2b(a) | ((unsigned int)f2b(b) << 16);
}
static __device__ __forceinline__ bf16x8 ld_frag_lds(const unsigned short* p) {
    frag_u t; t.u = *(const uint4*)p; return t.v;
}
static __device__ __forceinline__ bf16x8 cvt_frag8(const float* p) {
    float4 a = *(const float4*)p, b = *(const float4*)(p + 4);
    frag_u t;
    t.u = make_uint4(pk2(a.x, a.y), pk2(a.z, a.w), pk2(b.x, b.y), pk2(b.z, b.w));
    return t.v;
}
static __device__ __forceinline__ bf16x8 zero_frag() {
    frag_u t; t.u = make_uint4(0u, 0u, 0u, 0u); return t.v;
}

// ---------------------------------------------------------------------------
// Kernel 1: decisions in fp64 (match np ref): cvar/tflag bytes, adjacency bits,
// and zero the fp32 accumulator.  ALL float inputs are fp32.
// ---------------------------------------------------------------------------
__global__ __launch_bounds__(256) void prep_kernel(
    const float* __restrict__ u_gumbel,      // [B,L,K]
    const float* __restrict__ u_adj,         // [B,G,K,K]
    const float* __restrict__ target_params, // [L,K]
    const float* __restrict__ enco_theta,    // [K,K]
    const float* __restrict__ enco_gamma,    // [K,K]
    const int*   __restrict__ target,        // [B]
    float*       __restrict__ acc,           // [B]
    unsigned char* __restrict__ cvarpk,      // [B][32]  cvar | tflag<<3
    unsigned long long* __restrict__ adjbits)// [B][8]
{
    __shared__ double ep[64];
    const int t = threadIdx.x;
    if (t < 64) {
        double th = (double)enco_theta[t];
        double ga = (double)enco_gamma[t];
        ep[t] = (1.0 / (1.0 + exp(-th))) * (1.0 / (1.0 + exp(-ga)));
    }
    if (t < 4) acc[blockIdx.x * 4 + t] = 0.0f;
    __syncthreads();

    const int l = t >> 3, k = t & 7;
    for (int ib = 0; ib < 4; ++ib) {
        int b = blockIdx.x * 4 + ib;
        double u = (double)u_gumbel[b * 256 + t];
        double g = -log(-log(u + 1e-10) + 1e-10);
        double v = (double)target_params[t] + g;   // TAU = 1
        int bk = k;
        #pragma unroll
        for (int off = 1; off < 8; off <<= 1) {
            double ov = __shfl_xor(v, off, 64);
            int   obk = __shfl_xor(bk, off, 64);
            if (ov > v || (ov == v && obk < bk)) { v = ov; bk = obk; }
        }
        if (k == 0) {
            int tg = target[b];
            cvarpk[b * 32 + l] = (unsigned char)(bk | ((bk == tg) ? 8 : 0));
        }
    }
    if (t < 32) {
        int g8 = t & 7;
        int b  = blockIdx.x * 4 + (t >> 3);
        unsigned long long bits = 0ULL;
        const float* ua = u_adj + b * 512 + g8 * 64;
        for (int i = 0; i < 64; ++i) {
            double u = (double)ua[i];
            if (u < ep[i]) bits |= (1ULL << i);
        }
        adjbits[b * 8 + g8] = bits;
    }
}

// ---------------------------------------------------------------------------
// Kernel 2: fused build-X + GEMM1 + GN1 + SiLU + GEMM2 + GN2 + SiLU + GEMM3 +
// tanh-scale + KLD + g-mean, atomicAdd into acc[b].
// Grid 512: l = blockIdx&31, grp = blockIdx>>5  (same-l WGs share blockIdx%8
// -> same XCD -> weights L2-resident). WG = latent l, batches [grp*64, +64)
// as 4 tiles of 128 rows (16 b x 8 g). 4 waves tile D[c][row] 2x2.
// Weights held in registers (converted fp32->bf16 once); activations
// round-trip one LDS buffer.
// ---------------------------------------------------------------------------
__global__ __launch_bounds__(256, 2) void fused_kernel(
    const float* __restrict__ z_sample,   // [B,32]
    const float* __restrict__ z_mean,     // [B,32]
    const float* __restrict__ z_logstd,   // [B,32]
    const float* __restrict__ z_shared,   // [B,32]
    const float* __restrict__ W1,         // [32][128][104]
    const float* __restrict__ pb1,        // [32][128]
    const float* __restrict__ g1w,
    const float* __restrict__ g1b,
    const float* __restrict__ W2,         // [32][128][128]
    const float* __restrict__ pb2,
    const float* __restrict__ g2w,
    const float* __restrict__ g2b,
    const float* __restrict__ W3,         // [32][2][128]
    const float* __restrict__ pb3,        // [32][2]
    const float* __restrict__ tsc,        // [32][2]
    const unsigned char*  __restrict__ cvarpk,     // [B][32]
    const unsigned long long* __restrict__ adjbits,// [B][8]
    float* __restrict__ acc)                       // [B]
{
    __shared__ __align__(16) unsigned short XH[128][136];   // X then H (bf16), stride 136
    __shared__ float2 gnA[2][128];
    __shared__ float2 gnB[2][128];
    __shared__ float p_g1w[128], p_g1b[128], p_g2w[128], p_g2b[128], p_b1[128], p_b2[128];
    __shared__ float p_w3[2][128];
    __shared__ float p_b3[2], p_ts[2];
    __shared__ __align__(16) unsigned long long cvs[64][4];      // cvar bytes for 64 b
    __shared__ __align__(16) unsigned long long abits_s[64][8];  // [b_loc][g]

    const int tid  = threadIdx.x;
    const int w    = tid >> 6, lane = tid & 63;
    const int lo   = lane & 15, hi = lane >> 4;
    const int wm   = w & 1, wn = w >> 1;           // 2x2 wave grid: wm = c-half, wn = row-half
    const int l    = blockIdx.x & 31;
    const int grp  = blockIdx.x >> 5;

    // ---- stage per-latent params + decisions ----
    if (tid < 128) {
        int c = tid;
        p_g1w[c] = g1w[l * 128 + c];  p_g1b[c] = g1b[l * 128 + c];
        p_b1[c]  = pb1[l * 128 + c];  p_w3[0][c] = W3[l * 256 + c];
    } else {
        int c = tid - 128;
        p_g2w[c] = g2w[l * 128 + c];  p_g2b[c] = g2b[l * 128 + c];
        p_b2[c]  = pb2[l * 128 + c];  p_w3[1][c] = W3[l * 256 + 128 + c];
    }
    if (tid == 0) {
        p_b3[0] = pb3[l * 2];  p_b3[1] = pb3[l * 2 + 1];
        p_ts[0] = tsc[l * 2];  p_ts[1] = tsc[l * 2 + 1];
    }
    if (tid < 128)
        ((uint4*)cvs)[tid] = ((const uint4*)(cvarpk + (size_t)grp * 64 * 32))[tid];
    ((uint4*)abits_s)[tid] = ((const uint4*)(adjbits + (size_t)grp * 64 * 8))[tid];

    // ---- persistent weight fragments in registers (fp32 -> bf16 RNE) ----
    bf16x8 W1f[4][4], W2f[4][4];
    {
        const float* w1p = W1 + (size_t)l * 128 * 104;
        const float* w2p = W2 + (size_t)l * 128 * 128;
        #pragma unroll
        for (int mt = 0; mt < 4; ++mt) {
            int m = 16 * (4 * wm + mt) + lo;
            #pragma unroll
            for (int ks = 0; ks < 4; ++ks) {
                int k1 = ks * 32 + hi * 8;
                W1f[mt][ks] = (ks < 3 || hi == 0) ? cvt_frag8(w1p + m * 104 + k1) : zero_frag();
                W2f[mt][ks] = cvt_frag8(w2p + m * 128 + k1);
            }
        }
    }
    __syncthreads();  // B0

    const float inv128 = 1.0f / 128.0f;

    for (int it = 0; it < 4; ++it) {
        // ================= build X tile (128 rows x 104 + zero pad), bf16 =========
        {
            int r    = ((tid & 127) >> 1) + ((tid >> 7) << 6);
            int half = tid & 1;
            int bl   = it * 16 + (r >> 3);
            int bg   = grp * 64 + bl;
            unsigned long long lamB = cvs[bl][l >> 3] >> (8 * (l & 7));
            int lam = (int)(lamB & 7);
            int tf  = (int)(lamB >> 3) & 1;
            if (half == 0) {
                unsigned long long bits = abits_s[bl][r & 7];
                const float4* zp = (const float4*)(z_sample + bg * 32);
                float zf[32];
                #pragma unroll
                for (int q = 0; q < 8; ++q) ((float4*)zf)[q] = zp[q];
                union { uint4 u[2]; unsigned short s[16]; } xm, xk;
                #pragma unroll
                for (int wq = 0; wq < 4; ++wq) {
                    unsigned long long cw = cvs[bl][wq];
                    #pragma unroll
                    for (int jb = 0; jb < 8; ++jb) {
                        int j   = wq * 8 + jb;
                        int kap = (int)((cw >> (8 * jb)) & 7);
                        bool m  = (((bits >> (kap * 8 + lam)) & 1ULL) != 0) && (j != l);
                        xm.s[j & 15] = m ? f2b(zf[j]) : (unsigned short)0;
                        xk.s[j & 15] = m ? (unsigned short)0x3F80 : (unsigned short)0;
                    }
                    if (wq == 1) {
                        uint4* d0 = (uint4*)&XH[r][0];
                        d0[0] = xm.u[0]; d0[1] = xm.u[1];
                        uint4* d1 = (uint4*)&XH[r][32];
                        d1[0] = xk.u[0]; d1[1] = xk.u[1];
                    } else if (wq == 3) {
                        uint4* d0 = (uint4*)&XH[r][16];
                        d0[0] = xm.u[0]; d0[1] = xm.u[1];
                        uint4* d1 = (uint4*)&XH[r][48];
                        d1[0] = xk.u[0]; d1[1] = xk.u[1];
                    }
                }
            } else {
                union { uint4 u; unsigned short s[8]; } tv;
                #pragma unroll
                for (int kk = 0; kk < 8; ++kk)
                    tv.s[kk] = (tf && kk == lam) ? (unsigned short)0x3F80 : (unsigned short)0;
                *(uint4*)&XH[r][64] = tv.u;
                const float4* sp = (const float4*)(z_shared + bg * 32);
                #pragma unroll
                for (int q = 0; q < 4; ++q) {
                    float4 a = sp[2 * q], b = sp[2 * q + 1];
                    *(uint4*)&XH[r][72 + 8 * q] =
                        make_uint4(pk2(a.x, a.y), pk2(a.z, a.w), pk2(b.x, b.y), pk2(b.z, b.w));
                }
                uint4 zz = make_uint4(0u, 0u, 0u, 0u);
                *(uint4*)&XH[r][104] = zz;
                *(uint4*)&XH[r][112] = zz;
                *(uint4*)&XH[r][120] = zz;
            }
        }
        __syncthreads();  // B1

        // ================= GEMM1: D[c][row] = W1 * X^T =================
        f32x4 accr[4][4];
        #pragma unroll
        for (int a = 0; a < 4; ++a)
            #pragma unroll
            for (int bq = 0; bq < 4; ++bq) accr[a][bq] = (f32x4){0.f, 0.f, 0.f, 0.f};
        #pragma unroll
        for (int ks = 0; ks < 4; ++ks) {
            bf16x8 bfr[4];
            #pragma unroll
            for (int nt = 0; nt < 4; ++nt)
                bfr[nt] = ld_frag_lds(&XH[16 * (4 * wn + nt) + lo][ks * 32 + hi * 8]);
            #pragma unroll
            for (int mt = 0; mt < 4; ++mt)
                #pragma unroll
                for (int nt = 0; nt < 4; ++nt)
                    accr[mt][nt] = __builtin_amdgcn_mfma_f32_16x16x32_bf16(
                        W1f[mt][ks], bfr[nt], accr[mt][nt], 0, 0, 0);
        }

        // ---- GN1 stats (bias included) ----
        float s1[4] = {0, 0, 0, 0}, s2[4] = {0, 0, 0, 0};
        #pragma unroll
        for (int mt = 0; mt < 4; ++mt) {
            int cb = 16 * (4 * wm + mt) + 4 * hi;
            #pragma unroll
            for (int rg = 0; rg < 4; ++rg) {
                float bias = p_b1[cb + rg];
                #pragma unroll
                for (int nt = 0; nt < 4; ++nt) {
                    float v = accr[mt][nt][rg] + bias;
                    accr[mt][nt][rg] = v;
                    s1[nt] += v; s2[nt] += v * v;
                }
            }
        }
        #pragma unroll
        for (int nt = 0; nt < 4; ++nt) {
            s1[nt] += __shfl_xor(s1[nt], 16, 64);  s1[nt] += __shfl_xor(s1[nt], 32, 64);
            s2[nt] += __shfl_xor(s2[nt], 16, 64);  s2[nt] += __shfl_xor(s2[nt], 32, 64);
        }
        if (hi == 0) {
            #pragma unroll
            for (int nt = 0; nt < 4; ++nt)
                gnA[wm][16 * (4 * wn + nt) + lo] = make_float2(s1[nt], s2[nt]);
        }
        __syncthreads();  // B2 (also guarantees all GEMM1 X-reads are done)

        float mu[4], rstd[4];
        #pragma unroll
        for (int nt = 0; nt < 4; ++nt) {
            float2 a0 = gnA[0][16 * (4 * wn + nt) + lo];
            float2 a1 = gnA[1][16 * (4 * wn + nt) + lo];
            float m_  = (a0.x + a1.x) * inv128;
            float var = (a0.y + a1.y) * inv128 - m_ * m_;
            mu[nt] = m_;  rstd[nt] = rsqrtf(var + 1e-5f);
        }
        // ---- normalize + SiLU -> H (overwrite X region of this wave's c-half) ----
        #pragma unroll
        for (int mt = 0; mt < 4; ++mt) {
            int cb = 16 * (4 * wm + mt) + 4 * hi;
            #pragma unroll
            for (int nt = 0; nt < 4; ++nt) {
                int n = 16 * (4 * wn + nt) + lo;
                unsigned short us[4];
                #pragma unroll
                for (int rg = 0; rg < 4; ++rg) {
                    int c = cb + rg;
                    float x  = (accr[mt][nt][rg] - mu[nt]) * rstd[nt] * p_g1w[c] + p_g1b[c];
                    float sl = x / (1.0f + __expf(-x));
                    us[rg] = f2b(sl);
                }
                unsigned int w0 = (unsigned int)us[0] | ((unsigned int)us[1] << 16);
                unsigned int w1v = (unsigned int)us[2] | ((unsigned int)us[3] << 16);
                *(uint2*)&XH[n][cb] = make_uint2(w0, w1v);
            }
        }
        __syncthreads();  // B3

        // ================= GEMM2: D[c][row] = W2 * H^T =================
        #pragma unroll
        for (int a = 0; a < 4; ++a)
            #pragma unroll
            for (int bq = 0; bq < 4; ++bq) accr[a][bq] = (f32x4){0.f, 0.f, 0.f, 0.f};
        #pragma unroll
        for (int ks = 0; ks < 4; ++ks) {
            bf16x8 bfr[4];
            #pragma unroll
            for (int nt = 0; nt < 4; ++nt)
                bfr[nt] = ld_frag_lds(&XH[16 * (4 * wn + nt) + lo][ks * 32 + hi * 8]);
            #pragma unroll
            for (int mt = 0; mt < 4; ++mt)
                #pragma unroll
                for (int nt = 0; nt < 4; ++nt)
                    accr[mt][nt] = __builtin_amdgcn_mfma_f32_16x16x32_bf16(
                        W2f[mt][ks], bfr[nt], accr[mt][nt], 0, 0, 0);
        }

        // ---- GN2 stats ----
        float t1[4] = {0, 0, 0, 0}, t2[4] = {0, 0, 0, 0};
        #pragma unroll
        for (int mt = 0; mt < 4; ++mt) {
            int cb = 16 * (4 * wm + mt) + 4 * hi;
            #pragma unroll
            for (int rg = 0; rg < 4; ++rg) {
                float bias = p_b2[cb + rg];
                #pragma unroll
                for (int nt = 0; nt < 4; ++nt) {
                    float v = accr[mt][nt][rg] + bias;
                    accr[mt][nt][rg] = v;
                    t1[nt] += v; t2[nt] += v * v;
                }
            }
        }
        #pragma unroll
        for (int nt = 0; nt < 4; ++nt) {
            t1[nt] += __shfl_xor(t1[nt], 16, 64);  t1[nt] += __shfl_xor(t1[nt], 32, 64);
            t2[nt] += __shfl_xor(t2[nt], 16, 64);  t2[nt] += __shfl_xor(t2[nt], 32, 64);
        }
        if (hi == 0) {
            #pragma unroll
            for (int nt = 0; nt < 4; ++nt)
                gnA[wm][16 * (4 * wn + nt) + lo] = make_float2(t1[nt], t2[nt]);
        }
        __syncthreads();  // B4

        // ---- normalize + SiLU + 128->2 dot (GEMM3) partials ----
        float pmp[4] = {0, 0, 0, 0}, plp[4] = {0, 0, 0, 0};
        float mu2[4], rstd2[4];
        #pragma unroll
        for (int nt = 0; nt < 4; ++nt) {
            float2 a0 = gnA[0][16 * (4 * wn + nt) + lo];
            float2 a1 = gnA[1][16 * (4 * wn + nt) + lo];
            float m_  = (a0.x + a1.x) * inv128;
            float var = (a0.y + a1.y) * inv128 - m_ * m_;
            mu2[nt] = m_;  rstd2[nt] = rsqrtf(var + 1e-5f);
        }
        #pragma unroll
        for (int mt = 0; mt < 4; ++mt) {
            int cb = 16 * (4 * wm + mt) + 4 * hi;
            #pragma unroll
            for (int rg = 0; rg < 4; ++rg) {
                int c = cb + rg;
                float wg = p_g2w[c], bgn = p_g2b[c], w30 = p_w3[0][c], w31 = p_w3[1][c];
                #pragma unroll
                for (int nt = 0; nt < 4; ++nt) {
                    float x  = (accr[mt][nt][rg] - mu2[nt]) * rstd2[nt] * wg + bgn;
                    float sl = x / (1.0f + __expf(-x));
                    pmp[nt] += sl * w30;
                    plp[nt] += sl * w31;
                }
            }
        }
        #pragma unroll
        for (int nt = 0; nt < 4; ++nt) {
            pmp[nt] += __shfl_xor(pmp[nt], 16, 64);  pmp[nt] += __shfl_xor(pmp[nt], 32, 64);
            plp[nt] += __shfl_xor(plp[nt], 16, 64);  plp[nt] += __shfl_xor(plp[nt], 32, 64);
        }
        if (hi == 0) {
            #pragma unroll
            for (int nt = 0; nt < 4; ++nt)
                gnB[wm][16 * (4 * wn + nt) + lo] = make_float2(pmp[nt], plp[nt]);
        }
        __syncthreads();  // B5 (also protects XH overwrite by next tile's build)

        // ---- tanh-scale + KLD + mean over g + accumulate ----
        if (wm == 0 && hi == 0) {
            float sc0 = __expf(p_ts[0]), sc1 = __expf(p_ts[1]);
            #pragma unroll
            for (int nt = 0; nt < 4; ++nt) {
                int n = 16 * (4 * wn + nt) + lo;
                float2 q0 = gnB[0][n], q1 = gnB[1][n];
                float pm = q0.x + q1.x + p_b3[0];
                float pl = q0.y + q1.y + p_b3[1];
                pm = tanhf(pm / sc0) * sc0;
                pl = tanhf(pl / sc1) * sc1;
                int bl = it * 16 + (n >> 3);
                int bg = grp * 64 + bl;
                float zm = z_mean[bg * 32 + l];
                float zl = z_logstd[bg * 32 + l];
                float vq = __expf(2.0f * zl);
                float d  = zm - pm;
                float kld = pl - zl + (vq + d * d) * 0.5f * __expf(-2.0f * pl) - 0.5f;
                kld += __shfl_xor(kld, 1, 64);
                kld += __shfl_xor(kld, 2, 64);
                kld += __shfl_xor(kld, 4, 64);
                if ((lo & 7) == 0) atomicAdd(&acc[bg], kld * 0.125f);
            }
        }
    }
}

// ---------------------------------------------------------------------------
// Kernel 3: fp32 accumulator -> fp32 output
// ---------------------------------------------------------------------------
__global__ __launch_bounds__(256) void finish_kernel(const float* __restrict__ acc,
                                                     float* __restrict__ out) {
    int i = blockIdx.x * 256 + threadIdx.x;
    if (i < B_DIM) out[i] = acc[i];
}

extern "C" void kernel_launch(void* const* d_in, const int* in_sizes, int n_in,
                              void* d_out, int out_size, void* d_ws, size_t ws_size,
                              hipStream_t stream) {
    const float* z_sample      = (const float*)d_in[0];
    const int*   target        = (const int*)d_in[1];
    const float* z_mean        = (const float*)d_in[2];
    const float* z_logstd      = (const float*)d_in[3];
    const float* z_shared      = (const float*)d_in[4];
    const float* u_gumbel      = (const float*)d_in[5];
    const float* u_adj         = (const float*)d_in[6];
    const float* target_params = (const float*)d_in[7];
    const float* enco_theta    = (const float*)d_in[8];
    const float* enco_gamma    = (const float*)d_in[9];
    const float* W1            = (const float*)d_in[10];
    const float* b1            = (const float*)d_in[11];
    const float* g1w           = (const float*)d_in[12];
    const float* g1b           = (const float*)d_in[13];
    const float* W2            = (const float*)d_in[14];
    const float* b2            = (const float*)d_in[15];
    const float* g2w           = (const float*)d_in[16];
    const float* g2b           = (const float*)d_in[17];
    const float* W3            = (const float*)d_in[18];
    const float* b3            = (const float*)d_in[19];
    const float* tsc           = (const float*)d_in[20];

    float*              acc     = (float*)d_ws;                               // 4 KB
    unsigned char*      cvarpk  = (unsigned char*)d_ws + 4096;                // 32 KB
    unsigned long long* adjbits = (unsigned long long*)((char*)d_ws + 4096 + 32768); // 64 KB

    prep_kernel<<<256, 256, 0, stream>>>(u_gumbel, u_adj, target_params,
                                         enco_theta, enco_gamma, target,
                                         acc, cvarpk, adjbits);
    fused_kernel<<<512, 256, 0, stream>>>(z_sample, z_mean, z_logstd, z_shared,
                                          W1, b1, g1w, g1b, W2, b2, g2w, g2b,
                                          W3, b3, tsc, cvarpk, adjbits, acc);
    finish_kernel<<<4, 256, 0, stream>>>(acc, (float*)d_out);
}

// Round 3
// 209.354 us; speedup vs baseline: 1.0275x; 1.0275x over previous
//
#include <hip/hip_runtime.h>
#include <hip/hip_bf16.h>

// Problem constants
#define B_DIM 1024
#define L_DIM 32
#define K_DIM 8
#define G_DIM 8
#define C_DIM 128
#define S_DIM 32
#define DIN   104   // 2L + K + S

typedef __bf16  bf16x8 __attribute__((ext_vector_type(8)));
typedef float   f32x4  __attribute__((ext_vector_type(4)));

union frag_u { uint4 u; bf16x8 v; };

static __device__ __forceinline__ unsigned short f2b(float f) {
    union { float f; unsigned int i; } v; v.f = f;
    unsigned int x = v.i;
    return (unsigned short)((x + 0x7FFFu + ((x >> 16) & 1u)) >> 16);  // RNE
}
static __device__ __forceinline__ unsigned int pk2(float a, float b) {
    return (unsigned int)f2b(a) | ((unsigned int)f2b(b) << 16);
}
static __device__ __forceinline__ bf16x8 ld_frag(const unsigned short* p) {
    frag_u t; t.u = *(const uint4*)p; return t.v;
}

// ---------------------------------------------------------------------------
// Kernel 1: decisions in fp64: cvar/tflag bytes, adjacency bits (wave ballot),
// zero the fp32 accumulator. One block per batch element.
// ---------------------------------------------------------------------------
__global__ __launch_bounds__(256) void prep_kernel(
    const float* __restrict__ u_gumbel,      // [B,L,K]
    const float* __restrict__ u_adj,         // [B,G,K,K]
    const float* __restrict__ target_params, // [L,K]
    const float* __restrict__ enco_theta,    // [K,K]
    const float* __restrict__ enco_gamma,    // [K,K]
    const int*   __restrict__ target,        // [B]
    float*       __restrict__ acc,           // [B]
    unsigned char* __restrict__ cvarpk,      // [B][32]  cvar | tflag<<3
    unsigned long long* __restrict__ adjbits)// [B][8]
{
    __shared__ double ep[64];
    const int t = threadIdx.x;
    const int b = blockIdx.x;
    if (t < 64) {
        double th = (double)enco_theta[t];
        double ga = (double)enco_gamma[t];
        ep[t] = (1.0 / (1.0 + exp(-th))) * (1.0 / (1.0 + exp(-ga)));
    }
    if (t == 0) acc[b] = 0.0f;
    __syncthreads();

    // gumbel argmax: thread t = l*8 + k; 8-lane subgroup reduction
    {
        const int l = t >> 3, k = t & 7;
        double u = (double)u_gumbel[b * 256 + t];
        double g = -log(-log(u + 1e-10) + 1e-10);
        double v = (double)target_params[t] + g;   // TAU = 1
        int bk = k;
        #pragma unroll
        for (int off = 1; off < 8; off <<= 1) {
            double ov = __shfl_xor(v, off, 64);
            int   obk = __shfl_xor(bk, off, 64);
            if (ov > v || (ov == v && obk < bk)) { v = ov; bk = obk; }
        }
        if (k == 0) {
            int tg = target[b];
            cvarpk[b * 32 + l] = (unsigned char)(bk | ((bk == tg) ? 8 : 0));
        }
    }
    // adjacency: wave w handles g = w and g = w+4; bit i (= k*8+l) from lane i
    {
        const int wv = t >> 6, lane = t & 63;
        #pragma unroll
        for (int q = 0; q < 2; ++q) {
            int gg = wv + 4 * q;
            double u = (double)u_adj[b * 512 + gg * 64 + lane];
            unsigned long long m = __ballot(u < ep[lane]);
            if (lane == 0) adjbits[b * 8 + gg] = m;
        }
    }
}

// ---------------------------------------------------------------------------
// Kernel 1b: convert W1/W2 fp32 -> bf16 into d_ws, in MFMA fragment order:
//   frag F = ((which*32 + l)*2 + wm)*16 + mt*4 + ks ; data = [lane][8]
//   element = W[l][ m = 16*(4*wm+mt) + (lane&15) ][ k = ks*32 + (lane>>4)*8 + j ]
//   (W1 zero-padded K: 104..127 -> 0)
// ---------------------------------------------------------------------------
__global__ __launch_bounds__(256) void wprep_kernel(
    const float* __restrict__ W1,    // [32][128][104]
    const float* __restrict__ W2,    // [32][128][128]
    unsigned short* __restrict__ wscr)
{
    int gtid  = blockIdx.x * 256 + threadIdx.x;   // [0, 131072)
    int lane  = gtid & 63;
    int ks    = (gtid >> 6) & 3;
    int mt    = (gtid >> 8) & 3;
    int wm    = (gtid >> 10) & 1;
    int l     = (gtid >> 11) & 31;
    int which = gtid >> 16;
    int m  = 16 * (4 * wm + mt) + (lane & 15);
    int k0 = ks * 32 + (lane >> 4) * 8;

    uint4 out;
    if (which == 0) {
        if (k0 >= 104) {
            out = make_uint4(0u, 0u, 0u, 0u);
        } else {
            const float* p = W1 + (size_t)l * 13312 + m * 104 + k0;
            float4 a = *(const float4*)p, bq = *(const float4*)(p + 4);
            out = make_uint4(pk2(a.x, a.y), pk2(a.z, a.w), pk2(bq.x, bq.y), pk2(bq.z, bq.w));
        }
    } else {
        const float* p = W2 + (size_t)l * 16384 + m * 128 + k0;
        float4 a = *(const float4*)p, bq = *(const float4*)(p + 4);
        out = make_uint4(pk2(a.x, a.y), pk2(a.z, a.w), pk2(bq.x, bq.y), pk2(bq.z, bq.w));
    }
    *(uint4*)(wscr + (size_t)gtid * 8) = out;   // gtid*8 == F*512 + lane*8
}

// ---------------------------------------------------------------------------
// Kernel 2: fused build-X + GEMM1 + GN1 + SiLU + GEMM2 + GN2 + SiLU + GEMM3 +
// tanh-scale + KLD + g-mean, atomicAdd into acc[b].
// Grid 512: l = blockIdx&31 (same-l WGs -> same XCD -> bf16 weights L2-resident),
// grp = blockIdx>>5. 4 tiles of 128 rows; 4 waves tile D[c][row] 2x2.
// Weights STREAMED from bf16 scratch per GEMM (no persistent register arrays).
// ---------------------------------------------------------------------------
__global__ __launch_bounds__(256, 2) void fused_kernel(
    const float* __restrict__ z_sample,   // [B,32]
    const float* __restrict__ z_mean,     // [B,32]
    const float* __restrict__ z_logstd,   // [B,32]
    const float* __restrict__ z_shared,   // [B,32]
    const float* __restrict__ pb1,        // [32][128]
    const float* __restrict__ g1w,
    const float* __restrict__ g1b,
    const float* __restrict__ pb2,
    const float* __restrict__ g2w,
    const float* __restrict__ g2b,
    const float* __restrict__ W3,         // [32][2][128]
    const float* __restrict__ pb3,        // [32][2]
    const float* __restrict__ tsc,        // [32][2]
    const unsigned short* __restrict__ wscr,       // bf16 frag-ordered weights
    const unsigned char*  __restrict__ cvarpk,     // [B][32]
    const unsigned long long* __restrict__ adjbits,// [B][8]
    float* __restrict__ acc)                       // [B]
{
    __shared__ __align__(16) unsigned short XH[128][136];   // X then H (bf16)
    __shared__ float2 gnA[2][128];
    __shared__ float2 gnB[2][128];
    __shared__ float p_g1w[128], p_g1b[128], p_g2w[128], p_g2b[128], p_b1[128], p_b2[128];
    __shared__ float p_w3[2][128];
    __shared__ float p_b3[2], p_ts[2];
    __shared__ __align__(16) unsigned long long cvs[64][4];
    __shared__ __align__(16) unsigned long long abits_s[64][8];

    const int tid  = threadIdx.x;
    const int w    = tid >> 6, lane = tid & 63;
    const int lo   = lane & 15, hi = lane >> 4;
    const int wm   = w & 1, wn = w >> 1;
    const int l    = blockIdx.x & 31;
    const int grp  = blockIdx.x >> 5;

    const unsigned short* w1s = wscr + (size_t)((l * 2 + wm) * 16) * 512 + lane * 8;
    const unsigned short* w2s = wscr + (size_t)(((32 + l) * 2 + wm) * 16) * 512 + lane * 8;

    // ---- stage per-latent params + decisions ----
    if (tid < 128) {
        int c = tid;
        p_g1w[c] = g1w[l * 128 + c];  p_g1b[c] = g1b[l * 128 + c];
        p_b1[c]  = pb1[l * 128 + c];  p_w3[0][c] = W3[l * 256 + c];
    } else {
        int c = tid - 128;
        p_g2w[c] = g2w[l * 128 + c];  p_g2b[c] = g2b[l * 128 + c];
        p_b2[c]  = pb2[l * 128 + c];  p_w3[1][c] = W3[l * 256 + 128 + c];
    }
    if (tid == 0) {
        p_b3[0] = pb3[l * 2];  p_b3[1] = pb3[l * 2 + 1];
        p_ts[0] = tsc[l * 2];  p_ts[1] = tsc[l * 2 + 1];
    }
    if (tid < 128)
        ((uint4*)cvs)[tid] = ((const uint4*)(cvarpk + (size_t)grp * 64 * 32))[tid];
    ((uint4*)abits_s)[tid] = ((const uint4*)(adjbits + (size_t)grp * 64 * 8))[tid];
    __syncthreads();  // B0

    const float inv128 = 1.0f / 128.0f;

    for (int it = 0; it < 4; ++it) {
        // ================= build X tile (128 rows x 104 + zero pad), bf16 =========
        {
            int r    = ((tid & 127) >> 1) + ((tid >> 7) << 6);
            int half = tid & 1;
            int bl   = it * 16 + (r >> 3);
            int bg   = grp * 64 + bl;
            unsigned long long lamB = cvs[bl][l >> 3] >> (8 * (l & 7));
            int lam = (int)(lamB & 7);
            int tf  = (int)(lamB >> 3) & 1;
            if (half == 0) {
                unsigned long long bits = abits_s[bl][r & 7];
                const float4* zp = (const float4*)(z_sample + bg * 32);
                float zf[32];
                #pragma unroll
                for (int q = 0; q < 8; ++q) ((float4*)zf)[q] = zp[q];
                union { uint4 u[2]; unsigned short s[16]; } xm, xk;
                #pragma unroll
                for (int wq = 0; wq < 4; ++wq) {
                    unsigned long long cw = cvs[bl][wq];
                    #pragma unroll
                    for (int jb = 0; jb < 8; ++jb) {
                        int j   = wq * 8 + jb;
                        int kap = (int)((cw >> (8 * jb)) & 7);
                        bool m  = (((bits >> (kap * 8 + lam)) & 1ULL) != 0) && (j != l);
                        xm.s[j & 15] = m ? f2b(zf[j]) : (unsigned short)0;
                        xk.s[j & 15] = m ? (unsigned short)0x3F80 : (unsigned short)0;
                    }
                    if (wq == 1) {
                        uint4* d0 = (uint4*)&XH[r][0];
                        d0[0] = xm.u[0]; d0[1] = xm.u[1];
                        uint4* d1 = (uint4*)&XH[r][32];
                        d1[0] = xk.u[0]; d1[1] = xk.u[1];
                    } else if (wq == 3) {
                        uint4* d0 = (uint4*)&XH[r][16];
                        d0[0] = xm.u[0]; d0[1] = xm.u[1];
                        uint4* d1 = (uint4*)&XH[r][48];
                        d1[0] = xk.u[0]; d1[1] = xk.u[1];
                    }
                }
            } else {
                union { uint4 u; unsigned short s[8]; } tv;
                #pragma unroll
                for (int kk = 0; kk < 8; ++kk)
                    tv.s[kk] = (tf && kk == lam) ? (unsigned short)0x3F80 : (unsigned short)0;
                *(uint4*)&XH[r][64] = tv.u;
                const float4* sp = (const float4*)(z_shared + bg * 32);
                #pragma unroll
                for (int q = 0; q < 4; ++q) {
                    float4 a = sp[2 * q], b = sp[2 * q + 1];
                    *(uint4*)&XH[r][72 + 8 * q] =
                        make_uint4(pk2(a.x, a.y), pk2(a.z, a.w), pk2(b.x, b.y), pk2(b.z, b.w));
                }
                uint4 zz = make_uint4(0u, 0u, 0u, 0u);
                *(uint4*)&XH[r][104] = zz;
                *(uint4*)&XH[r][112] = zz;
                *(uint4*)&XH[r][120] = zz;
            }
        }

        // ---- stream W1 fragments (L2) while barrier settles ----
        bf16x8 wt[4][4];
        #pragma unroll
        for (int mt = 0; mt < 4; ++mt)
            #pragma unroll
            for (int ks = 0; ks < 4; ++ks)
                wt[mt][ks] = ld_frag(w1s + (mt * 4 + ks) * 512);
        __syncthreads();  // B1

        // ================= GEMM1: D[c][row] = W1 * X^T =================
        f32x4 accr[4][4];
        #pragma unroll
        for (int a = 0; a < 4; ++a)
            #pragma unroll
            for (int bq = 0; bq < 4; ++bq) accr[a][bq] = (f32x4){0.f, 0.f, 0.f, 0.f};
        #pragma unroll
        for (int ks = 0; ks < 4; ++ks) {
            bf16x8 bfr[4];
            #pragma unroll
            for (int nt = 0; nt < 4; ++nt)
                bfr[nt] = ld_frag(&XH[16 * (4 * wn + nt) + lo][ks * 32 + hi * 8]);
            #pragma unroll
            for (int mt = 0; mt < 4; ++mt)
                #pragma unroll
                for (int nt = 0; nt < 4; ++nt)
                    accr[mt][nt] = __builtin_amdgcn_mfma_f32_16x16x32_bf16(
                        wt[mt][ks], bfr[nt], accr[mt][nt], 0, 0, 0);
        }
        // ---- stream W2 fragments; GN1 hides the latency ----
        #pragma unroll
        for (int mt = 0; mt < 4; ++mt)
            #pragma unroll
            for (int ks = 0; ks < 4; ++ks)
                wt[mt][ks] = ld_frag(w2s + (mt * 4 + ks) * 512);

        // ---- GN1 stats (bias included) ----
        float s1[4] = {0, 0, 0, 0}, s2[4] = {0, 0, 0, 0};
        #pragma unroll
        for (int mt = 0; mt < 4; ++mt) {
            int cb = 16 * (4 * wm + mt) + 4 * hi;
            #pragma unroll
            for (int rg = 0; rg < 4; ++rg) {
                float bias = p_b1[cb + rg];
                #pragma unroll
                for (int nt = 0; nt < 4; ++nt) {
                    float v = accr[mt][nt][rg] + bias;
                    accr[mt][nt][rg] = v;
                    s1[nt] += v; s2[nt] += v * v;
                }
            }
        }
        #pragma unroll
        for (int nt = 0; nt < 4; ++nt) {
            s1[nt] += __shfl_xor(s1[nt], 16, 64);  s1[nt] += __shfl_xor(s1[nt], 32, 64);
            s2[nt] += __shfl_xor(s2[nt], 16, 64);  s2[nt] += __shfl_xor(s2[nt], 32, 64);
        }
        if (hi == 0) {
            #pragma unroll
            for (int nt = 0; nt < 4; ++nt)
                gnA[wm][16 * (4 * wn + nt) + lo] = make_float2(s1[nt], s2[nt]);
        }
        __syncthreads();  // B2

        float mu[4], rstd[4];
        #pragma unroll
        for (int nt = 0; nt < 4; ++nt) {
            float2 a0 = gnA[0][16 * (4 * wn + nt) + lo];
            float2 a1 = gnA[1][16 * (4 * wn + nt) + lo];
            float m_  = (a0.x + a1.x) * inv128;
            float var = (a0.y + a1.y) * inv128 - m_ * m_;
            mu[nt] = m_;  rstd[nt] = rsqrtf(var + 1e-5f);
        }
        // ---- normalize + SiLU -> H ----
        #pragma unroll
        for (int mt = 0; mt < 4; ++mt) {
            int cb = 16 * (4 * wm + mt) + 4 * hi;
            #pragma unroll
            for (int nt = 0; nt < 4; ++nt) {
                int n = 16 * (4 * wn + nt) + lo;
                unsigned short us[4];
                #pragma unroll
                for (int rg = 0; rg < 4; ++rg) {
                    int c = cb + rg;
                    float x  = (accr[mt][nt][rg] - mu[nt]) * rstd[nt] * p_g1w[c] + p_g1b[c];
                    float sl = x / (1.0f + __expf(-x));
                    us[rg] = f2b(sl);
                }
                unsigned int w0 = (unsigned int)us[0] | ((unsigned int)us[1] << 16);
                unsigned int w1v = (unsigned int)us[2] | ((unsigned int)us[3] << 16);
                *(uint2*)&XH[n][cb] = make_uint2(w0, w1v);
            }
        }
        __syncthreads();  // B3

        // ================= GEMM2: D[c][row] = W2 * H^T =================
        #pragma unroll
        for (int a = 0; a < 4; ++a)
            #pragma unroll
            for (int bq = 0; bq < 4; ++bq) accr[a][bq] = (f32x4){0.f, 0.f, 0.f, 0.f};
        #pragma unroll
        for (int ks = 0; ks < 4; ++ks) {
            bf16x8 bfr[4];
            #pragma unroll
            for (int nt = 0; nt < 4; ++nt)
                bfr[nt] = ld_frag(&XH[16 * (4 * wn + nt) + lo][ks * 32 + hi * 8]);
            #pragma unroll
            for (int mt = 0; mt < 4; ++mt)
                #pragma unroll
                for (int nt = 0; nt < 4; ++nt)
                    accr[mt][nt] = __builtin_amdgcn_mfma_f32_16x16x32_bf16(
                        wt[mt][ks], bfr[nt], accr[mt][nt], 0, 0, 0);
        }

        // ---- GN2 stats ----
        float t1[4] = {0, 0, 0, 0}, t2[4] = {0, 0, 0, 0};
        #pragma unroll
        for (int mt = 0; mt < 4; ++mt) {
            int cb = 16 * (4 * wm + mt) + 4 * hi;
            #pragma unroll
            for (int rg = 0; rg < 4; ++rg) {
                float bias = p_b2[cb + rg];
                #pragma unroll
                for (int nt = 0; nt < 4; ++nt) {
                    float v = accr[mt][nt][rg] + bias;
                    accr[mt][nt][rg] = v;
                    t1[nt] += v; t2[nt] += v * v;
                }
            }
        }
        #pragma unroll
        for (int nt = 0; nt < 4; ++nt) {
            t1[nt] += __shfl_xor(t1[nt], 16, 64);  t1[nt] += __shfl_xor(t1[nt], 32, 64);
            t2[nt] += __shfl_xor(t2[nt], 16, 64);  t2[nt] += __shfl_xor(t2[nt], 32, 64);
        }
        if (hi == 0) {
            #pragma unroll
            for (int nt = 0; nt < 4; ++nt)
                gnA[wm][16 * (4 * wn + nt) + lo] = make_float2(t1[nt], t2[nt]);
        }
        __syncthreads();  // B4

        // ---- normalize + SiLU + 128->2 dot partials ----
        float pmp[4] = {0, 0, 0, 0}, plp[4] = {0, 0, 0, 0};
        float mu2[4], rstd2[4];
        #pragma unroll
        for (int nt = 0; nt < 4; ++nt) {
            float2 a0 = gnA[0][16 * (4 * wn + nt) + lo];
            float2 a1 = gnA[1][16 * (4 * wn + nt) + lo];
            float m_  = (a0.x + a1.x) * inv128;
            float var = (a0.y + a1.y) * inv128 - m_ * m_;
            mu2[nt] = m_;  rstd2[nt] = rsqrtf(var + 1e-5f);
        }
        #pragma unroll
        for (int mt = 0; mt < 4; ++mt) {
            int cb = 16 * (4 * wm + mt) + 4 * hi;
            #pragma unroll
            for (int rg = 0; rg < 4; ++rg) {
                int c = cb + rg;
                float wg = p_g2w[c], bgn = p_g2b[c], w30 = p_w3[0][c], w31 = p_w3[1][c];
                #pragma unroll
                for (int nt = 0; nt < 4; ++nt) {
                    float x  = (accr[mt][nt][rg] - mu2[nt]) * rstd2[nt] * wg + bgn;
                    float sl = x / (1.0f + __expf(-x));
                    pmp[nt] += sl * w30;
                    plp[nt] += sl * w31;
                }
            }
        }
        #pragma unroll
        for (int nt = 0; nt < 4; ++nt) {
            pmp[nt] += __shfl_xor(pmp[nt], 16, 64);  pmp[nt] += __shfl_xor(pmp[nt], 32, 64);
            plp[nt] += __shfl_xor(plp[nt], 16, 64);  plp[nt] += __shfl_xor(plp[nt], 32, 64);
        }
        if (hi == 0) {
            #pragma unroll
            for (int nt = 0; nt < 4; ++nt)
                gnB[wm][16 * (4 * wn + nt) + lo] = make_float2(pmp[nt], plp[nt]);
        }
        __syncthreads();  // B5

        // ---- tanh-scale + KLD + mean over g + accumulate ----
        if (wm == 0 && hi == 0) {
            float sc0 = __expf(p_ts[0]), sc1 = __expf(p_ts[1]);
            #pragma unroll
            for (int nt = 0; nt < 4; ++nt) {
                int n = 16 * (4 * wn + nt) + lo;
                float2 q0 = gnB[0][n], q1 = gnB[1][n];
                float pm = q0.x + q1.x + p_b3[0];
                float pl = q0.y + q1.y + p_b3[1];
                pm = tanhf(pm / sc0) * sc0;
                pl = tanhf(pl / sc1) * sc1;
                int bl = it * 16 + (n >> 3);
                int bg = grp * 64 + bl;
                float zm = z_mean[bg * 32 + l];
                float zl = z_logstd[bg * 32 + l];
                float vq = __expf(2.0f * zl);
                float d  = zm - pm;
                float kld = pl - zl + (vq + d * d) * 0.5f * __expf(-2.0f * pl) - 0.5f;
                kld += __shfl_xor(kld, 1, 64);
                kld += __shfl_xor(kld, 2, 64);
                kld += __shfl_xor(kld, 4, 64);
                if ((lo & 7) == 0) atomicAdd(&acc[bg], kld * 0.125f);
            }
        }
    }
}

// ---------------------------------------------------------------------------
// Kernel 3: fp32 accumulator -> fp32 output
// ---------------------------------------------------------------------------
__global__ __launch_bounds__(256) void finish_kernel(const float* __restrict__ acc,
                                                     float* __restrict__ out) {
    int i = blockIdx.x * 256 + threadIdx.x;
    if (i < B_DIM) out[i] = acc[i];
}

extern "C" void kernel_launch(void* const* d_in, const int* in_sizes, int n_in,
                              void* d_out, int out_size, void* d_ws, size_t ws_size,
                              hipStream_t stream) {
    const float* z_sample      = (const float*)d_in[0];
    const int*   target        = (const int*)d_in[1];
    const float* z_mean        = (const float*)d_in[2];
    const float* z_logstd      = (const float*)d_in[3];
    const float* z_shared      = (const float*)d_in[4];
    const float* u_gumbel      = (const float*)d_in[5];
    const float* u_adj         = (const float*)d_in[6];
    const float* target_params = (const float*)d_in[7];
    const float* enco_theta    = (const float*)d_in[8];
    const float* enco_gamma    = (const float*)d_in[9];
    const float* W1            = (const float*)d_in[10];
    const float* pb1           = (const float*)d_in[11];
    const float* g1w           = (const float*)d_in[12];
    const float* g1b           = (const float*)d_in[13];
    const float* W2            = (const float*)d_in[14];
    const float* pb2           = (const float*)d_in[15];
    const float* g2w           = (const float*)d_in[16];
    const float* g2b           = (const float*)d_in[17];
    const float* W3            = (const float*)d_in[18];
    const float* pb3           = (const float*)d_in[19];
    const float* tsc           = (const float*)d_in[20];

    float*              acc     = (float*)d_ws;                                // 4 KB
    unsigned char*      cvarpk  = (unsigned char*)d_ws + 4096;                 // 32 KB
    unsigned long long* adjbits = (unsigned long long*)((char*)d_ws + 36864);  // 64 KB
    unsigned short*     wscr    = (unsigned short*)((char*)d_ws + 102400);     // 2 MB

    prep_kernel<<<1024, 256, 0, stream>>>(u_gumbel, u_adj, target_params,
                                          enco_theta, enco_gamma, target,
                                          acc, cvarpk, adjbits);
    wprep_kernel<<<512, 256, 0, stream>>>(W1, W2, wscr);
    fused_kernel<<<512, 256, 0, stream>>>(z_sample, z_mean, z_logstd, z_shared,
                                          pb1, g1w, g1b, pb2, g2w, g2b,
                                          W3, pb3, tsc, wscr, cvarpk, adjbits, acc);
    finish_kernel<<<4, 256, 0, stream>>>(acc, (float*)d_out);
}